// Round 5
// baseline (352.415 us; speedup 1.0000x reference)
//
#include <hip/hip_runtime.h>

// Fused SAGAN attention block, MI355X/gfx950.
// B=8, C=128, N=4096 (64x64), IN=512. bf16 MFMA 16x16x32, fp32 accum.
// Fragment layouts (verified rounds 1-4 pass):
//   A-frag: A[m = lane&15][k = (lane>>4)*8 + j]   (short8, 16B/lane)
//   B-frag: B[k = (lane>>4)*8 + j][n = lane&15]
//   C/D   : D[row = (lane>>4)*4 + reg][col = lane&15]
// R5: PV uses a permuted k-map pi(qd*8+j) = (j>=4)*16 + qd*4 + (j&3) so the
// B-operand (P^T) is the lane's OWN packed S^T C/D registers (no LDS round
// trip, pbuf deleted -> LDS 32KB, 4-5 blocks/CU); V A-frags absorb pi via
// two ds_read_b64 from the unchanged vbuf. V staged in LDS again (R4's
// direct-global V-frags split 16 ways per instr -> reverted).

typedef __attribute__((ext_vector_type(4))) float f32x4;
typedef __attribute__((ext_vector_type(8))) short bf16x8;
typedef __attribute__((ext_vector_type(2))) unsigned int u32x2;
typedef __attribute__((ext_vector_type(4))) unsigned int u32x4;
typedef __attribute__((ext_vector_type(4))) unsigned short u16x4;

#define MFMA16(a, b, c) __builtin_amdgcn_mfma_f32_16x16x32_bf16((a), (b), (c), 0, 0, 0)
#define LOG2E 1.44269504088896340736f
#define SOFTMAX_SHIFT 40.0f

#if __has_builtin(__builtin_amdgcn_exp2f)
#define EXP2F(x) __builtin_amdgcn_exp2f(x)
#else
#define EXP2F(x) exp2f(x)
#endif

__device__ __forceinline__ unsigned short f2bf(float f) {
  union { float f; unsigned int u; } v; v.f = f;
  unsigned int r = v.u + 0x7FFFu + ((v.u >> 16) & 1u);  // RNE
  return (unsigned short)(r >> 16);
}

// pack two f32 -> packed bf16x2 (round-half-up): 2 adds + 1 v_perm_b32.
__device__ __forceinline__ unsigned int pkbf(float a, float b) {
  unsigned int ua = __float_as_uint(a) + 0x8000u;
  unsigned int ub = __float_as_uint(b) + 0x8000u;
  return __builtin_amdgcn_perm(ub, ua, 0x07060302u);  // lo=bf(a), hi=bf(b)
}

__device__ __forceinline__ void gload_lds16(const void* g, void* l) {
  __builtin_amdgcn_global_load_lds(
      (const __attribute__((address_space(1))) unsigned int*)(unsigned long long)g,
      (__attribute__((address_space(3))) unsigned int*)(unsigned int)(unsigned long long)l,
      16, 0, 0);
}

union frag_cast { u32x4 u; bf16x8 h; };

// ---------------------------------------------------------------- kernel 0
__global__ void cvt_w_kernel(const float* __restrict__ Win, const float* __restrict__ Wq,
                             const float* __restrict__ Wk, const float* __restrict__ Wv,
                             unsigned short* __restrict__ o) {
  int t = blockIdx.x * 256 + threadIdx.x;
  if (t < 65536)       o[t] = f2bf(Win[t]);
  else if (t < 81920)  o[t] = f2bf(Wq[t - 65536]);
  else if (t < 98304)  o[t] = f2bf(Wk[t - 81920]);
  else if (t < 114688) o[t] = f2bf(Wv[t - 98304]);
}

// ---------------------------------------------------------------- kernel 1
// Fused projections, 64-n tile per 256-thread block (grid 64x8).
// xf = W_in x + b_in (fp32 (C,N)); xh tile in LDS; q,k (N,C); v (C,N).
// R5: next x-chunk prefetched across the MFMA loop.
__global__ __launch_bounds__(256) void proj_kernel(
    const float* __restrict__ x, const unsigned short* __restrict__ Wb,
    const float* __restrict__ b_in, const float* __restrict__ bq,
    const float* __restrict__ bk, const float* __restrict__ bv,
    float* __restrict__ xf, unsigned short* __restrict__ qt,
    unsigned short* __restrict__ kt, unsigned short* __restrict__ vv) {
  __shared__ alignas(16) unsigned short xt[16 * 512];   // x chunk 128i x 64n, swizzled
  __shared__ alignas(16) unsigned short xt2[16 * 512];  // xh tile 128c x 64n
  const int tid = threadIdx.x;
  const int w = tid >> 6, L = tid & 63, l15 = L & 15, qd = L >> 4;
  const int n0 = blockIdx.x * 64;
  const int b = blockIdx.y;
  const float* xb = x + (size_t)b * 512 * 4096;

  const int io = tid >> 4, nq = tid & 15;          // i-oct 0..15, n-quad 0..15
  const int il0 = io * 8, kkA = io >> 2, qr = io & 3;
  const int nbA = nq >> 2;
  const int Lsw8 = (L ^ ((L >> 2) & 7)) * 8;       // swizzled read slot

  f32x4 acc[2][4];
#pragma unroll
  for (int ma = 0; ma < 2; ++ma)
#pragma unroll
    for (int nb = 0; nb < 4; ++nb) acc[ma][nb] = (f32x4){0.f, 0.f, 0.f, 0.f};

  f32x4 xv[8];
#pragma unroll
  for (int r = 0; r < 8; ++r)
    xv[r] = *(const f32x4*)(xb + (size_t)(il0 + r) * 4096 + n0 + nq * 4);

  for (int c4 = 0; c4 < 4; ++c4) {
    const int i0 = c4 * 128;
    __syncthreads();
#pragma unroll
    for (int j = 0; j < 4; ++j) {
      const int n15 = (nq & 3) * 4 + j;
      const int s = qr * 16 + n15;
      const int sp = s ^ ((s >> 2) & 7);           // bank swizzle
      u32x4 d = {pkbf(xv[0][j], xv[1][j]), pkbf(xv[2][j], xv[3][j]),
                 pkbf(xv[4][j], xv[5][j]), pkbf(xv[6][j], xv[7][j])};
      *(u32x4*)&xt[(nbA * 4 + kkA) * 512 + sp * 8] = d;
    }
    __syncthreads();
    if (c4 < 3) {                                  // prefetch next chunk
      const int i0n = i0 + 128;
#pragma unroll
      for (int r = 0; r < 8; ++r)
        xv[r] = *(const f32x4*)(xb + (size_t)(i0n + il0 + r) * 4096 + n0 + nq * 4);
    }
#pragma unroll
    for (int kk = 0; kk < 4; ++kk) {
      bf16x8 a[2];
#pragma unroll
      for (int ma = 0; ma < 2; ++ma)
        a[ma] = *(const bf16x8*)(Wb + (size_t)(w * 32 + ma * 16 + l15) * 512 + i0 + kk * 32 + qd * 8);
#pragma unroll
      for (int nb = 0; nb < 4; ++nb) {
        bf16x8 bfv = *(const bf16x8*)&xt[(nb * 4 + kk) * 512 + Lsw8];
#pragma unroll
        for (int ma = 0; ma < 2; ++ma) acc[ma][nb] = MFMA16(a[ma], bfv, acc[ma][nb]);
      }
    }
  }
  // epilogue A: xf (fp32 global) + xh tile into xt2 (B-frag order)
  {
    float* xfb = xf + (size_t)b * 128 * 4096;
#pragma unroll
    for (int ma = 0; ma < 2; ++ma) {
      const int c0 = w * 32 + ma * 16 + qd * 4;
      const float bi0 = b_in[c0], bi1 = b_in[c0 + 1], bi2 = b_in[c0 + 2], bi3 = b_in[c0 + 3];
      const int qdrow = ma * 2 + (qd >> 1);
      const int joff = (qd & 1) * 4;
#pragma unroll
      for (int nb = 0; nb < 4; ++nb) {
        const int n = n0 + nb * 16 + l15;
        const float v0 = acc[ma][nb][0] + bi0, v1 = acc[ma][nb][1] + bi1;
        const float v2 = acc[ma][nb][2] + bi2, v3 = acc[ma][nb][3] + bi3;
        xfb[(size_t)(c0 + 0) * 4096 + n] = v0;
        xfb[(size_t)(c0 + 1) * 4096 + n] = v1;
        xfb[(size_t)(c0 + 2) * 4096 + n] = v2;
        xfb[(size_t)(c0 + 3) * 4096 + n] = v3;
        u32x2 h = {pkbf(v0, v1), pkbf(v2, v3)};
        *(u32x2*)&xt2[(nb * 4 + w) * 512 + qdrow * 128 + l15 * 8 + joff] = h;
      }
    }
  }
  __syncthreads();

  // ---- phase B: q, k (M = c strip w*32..+32, N = n 64)
  for (int which = 0; which < 2; ++which) {
    const unsigned short* W = Wb + 65536 + which * 16384;
    const float* bias = which ? bk : bq;
    unsigned short* dst = (which ? kt : qt) + (size_t)b * 4096 * 128;
    f32x4 a2[2][4];
#pragma unroll
    for (int ma = 0; ma < 2; ++ma)
#pragma unroll
      for (int nb = 0; nb < 4; ++nb) a2[ma][nb] = (f32x4){0.f, 0.f, 0.f, 0.f};
#pragma unroll
    for (int kk = 0; kk < 4; ++kk) {
      bf16x8 a[2];
#pragma unroll
      for (int ma = 0; ma < 2; ++ma)
        a[ma] = *(const bf16x8*)(W + (size_t)(w * 32 + ma * 16 + l15) * 128 + kk * 32 + qd * 8);
#pragma unroll
      for (int nb = 0; nb < 4; ++nb) {
        bf16x8 bfv = *(const bf16x8*)&xt2[(nb * 4 + kk) * 512 + L * 8];
#pragma unroll
        for (int ma = 0; ma < 2; ++ma) a2[ma][nb] = MFMA16(a[ma], bfv, a2[ma][nb]);
      }
    }
#pragma unroll
    for (int ma = 0; ma < 2; ++ma) {
      const int c0 = w * 32 + ma * 16 + qd * 4;
      const float b0 = bias[c0], b1 = bias[c0 + 1], b2 = bias[c0 + 2], b3 = bias[c0 + 3];
#pragma unroll
      for (int nb = 0; nb < 4; ++nb) {
        const int n = n0 + nb * 16 + l15;
        u32x2 h = {pkbf(a2[ma][nb][0] + b0, a2[ma][nb][1] + b1),
                   pkbf(a2[ma][nb][2] + b2, a2[ma][nb][3] + b3)};
        *(u32x2*)&dst[(size_t)n * 128 + c0] = h;
      }
    }
  }
  // ---- phase B: v (M = n strip w*16, N = c 128) -> channel-major
  {
    const unsigned short* Wv = Wb + 98304;
    f32x4 a2[8];
#pragma unroll
    for (int cb = 0; cb < 8; ++cb) a2[cb] = (f32x4){0.f, 0.f, 0.f, 0.f};
#pragma unroll
    for (int kk = 0; kk < 4; ++kk) {
      bf16x8 a = *(const bf16x8*)&xt2[(w * 4 + kk) * 512 + L * 8];  // A-frag: n-strip w
#pragma unroll
      for (int cb = 0; cb < 8; ++cb) {
        bf16x8 bfv = *(const bf16x8*)(Wv + (size_t)(cb * 16 + l15) * 128 + kk * 32 + qd * 8);
        a2[cb] = MFMA16(a, bfv, a2[cb]);
      }
    }
    unsigned short* db = vv + (size_t)b * 128 * 4096;
    const int nbase = n0 + w * 16 + qd * 4;
#pragma unroll
    for (int cb = 0; cb < 8; ++cb) {
      const int c = cb * 16 + l15;
      const float bvv = bv[c];
      u32x2 h = {pkbf(a2[cb][0] + bvv, a2[cb][1] + bvv), pkbf(a2[cb][2] + bvv, a2[cb][3] + bvv)};
      *(u32x2*)&db[(size_t)c * 4096 + nbase] = h;
    }
  }
}

// ---------------------------------------------------------------- kernel 2
// Flash attention, no-max softmax. Block = (batch, 128-q tile, m-split).
// K,V staged in LDS (32KB total). PV B-operand = own packed S^T C/D regs
// (permuted k-map); V A-frags = 2x ds_read_b64 honoring the same k-map.
// Output acc = O[c rows][n cols] per tile; pa bf16 (N,C).
__global__ __launch_bounds__(256, 4) void attn_kernel(
    const unsigned short* __restrict__ qt, const unsigned short* __restrict__ kt,
    const unsigned short* __restrict__ vv, unsigned short* __restrict__ pa,
    float* __restrict__ lp, int nsplit) {
  __shared__ alignas(16) unsigned short kbuf[16 * 512];   // 16 KB (mb, kk)
  __shared__ alignas(16) unsigned short vbuf[16 * 512];   // 16 KB (cb, kkm)

  const int tid = threadIdx.x;
  const int w = tid >> 6, L = tid & 63, l15 = L & 15, qd = L >> 4;
  const int bidx = blockIdx.x;
  const int b = bidx & 7;                  // XCD-pinned batch: K/V L2-resident
  const int r2 = bidx >> 3;
  const int qtile = r2 & 31, split = r2 >> 5;
  const int n00 = qtile * 128;
  const int mlen = 4096 / nsplit;
  const int mbeg = split * mlen;

  const unsigned short* qtb = qt + (size_t)b * 4096 * 128;
  const unsigned short* ktb = kt + (size_t)b * 4096 * 128;
  const unsigned short* vvb = vv + (size_t)b * 128 * 4096;

  bf16x8 qf[2][4];
#pragma unroll
  for (int nh = 0; nh < 2; ++nh) {
    const unsigned short* qrow = qtb + (size_t)(n00 + w * 32 + nh * 16 + l15) * 128 + qd * 8;
#pragma unroll
    for (int kk = 0; kk < 4; ++kk) qf[nh][kk] = *(const bf16x8*)(qrow + kk * 32);
  }

  f32x4 acc[2][8];
#pragma unroll
  for (int nh = 0; nh < 2; ++nh)
#pragma unroll
    for (int cb = 0; cb < 8; ++cb) acc[nh][cb] = (f32x4){0.f, 0.f, 0.f, 0.f};
  float lsum[2] = {0.f, 0.f};
  const float sb = SOFTMAX_SHIFT * LOG2E;
  // V A-frag base offset under permuted k-map (j<4 half; +256 shorts for j>=4)
  const int va = ((qd >> 1) * 16 + l15) * 8 + (qd & 1) * 4;

  for (int m0 = mbeg; m0 < mbeg + mlen; m0 += 64) {
    __syncthreads();                       // prev iter's kbuf/vbuf reads done
#pragma unroll
    for (int j = 0; j < 4; ++j) {
      const int blk = w * 4 + j;
      const int mb = blk >> 2, kk = blk & 3;
      gload_lds16(ktb + (size_t)(m0 + mb * 16 + l15) * 128 + kk * 32 + qd * 8,
                  &kbuf[blk * 512]);
      const int cb2 = blk >> 1, kkm = blk & 1;
      gload_lds16(vvb + (size_t)(cb2 * 16 + l15) * 4096 + m0 + kkm * 32 + qd * 8,
                  &vbuf[blk * 512]);
    }
    __syncthreads();                       // staging complete

    // S^T = K · Q^T : D rows = m-local, cols = n-local (per nh half)
    f32x4 s[2][4];
#pragma unroll
    for (int mb = 0; mb < 4; ++mb) {
      s[0][mb] = (f32x4){0.f, 0.f, 0.f, 0.f};
      s[1][mb] = (f32x4){0.f, 0.f, 0.f, 0.f};
#pragma unroll
      for (int kk = 0; kk < 4; ++kk) {
        bf16x8 kf = *(const bf16x8*)&kbuf[(mb * 4 + kk) * 512 + L * 8];
        s[0][mb] = MFMA16(kf, qf[0][kk], s[0][mb]);
        s[1][mb] = MFMA16(kf, qf[1][kk], s[1][mb]);
      }
    }
    // p = exp2(s*log2e - shift); lane-local row sums; pack into OWN regs.
    // pk01/pk23[nh][mb] hold P^T rows (mb*16 + qd*4 + {0,1}/{2,3}), col l15.
    unsigned int pk01[2][4], pk23[2][4];
#pragma unroll
    for (int nh = 0; nh < 2; ++nh) {
#pragma unroll
      for (int mb = 0; mb < 4; ++mb) {
        float p0 = EXP2F(__builtin_fmaf(s[nh][mb][0], LOG2E, -sb));
        float p1 = EXP2F(__builtin_fmaf(s[nh][mb][1], LOG2E, -sb));
        float p2 = EXP2F(__builtin_fmaf(s[nh][mb][2], LOG2E, -sb));
        float p3 = EXP2F(__builtin_fmaf(s[nh][mb][3], LOG2E, -sb));
        lsum[nh] += (p0 + p1) + (p2 + p3);
        pk01[nh][mb] = pkbf(p0, p1);
        pk23[nh][mb] = pkbf(p2, p3);
      }
    }
    // O[c][n] += V · P^T with k-map pi(qd*8+j) = (j>=4)*16 + qd*4 + (j&3).
    // B-frag(ks,nh) = (pk01[ks*2], pk23[ks*2], pk01[ks*2+1], pk23[ks*2+1]).
#pragma unroll
    for (int ks = 0; ks < 2; ++ks) {
      frag_cast bf0, bf1;
      bf0.u = (u32x4){pk01[0][ks * 2], pk23[0][ks * 2], pk01[0][ks * 2 + 1], pk23[0][ks * 2 + 1]};
      bf1.u = (u32x4){pk01[1][ks * 2], pk23[1][ks * 2], pk01[1][ks * 2 + 1], pk23[1][ks * 2 + 1]};
#pragma unroll
      for (int cb = 0; cb < 8; ++cb) {
        const int vb = (cb * 2 + ks) * 512 + va;
        frag_cast vf;
        u32x2 lo = *(const u32x2*)&vbuf[vb];
        u32x2 hi = *(const u32x2*)&vbuf[vb + 256];
        vf.u = (u32x4){lo[0], lo[1], hi[0], hi[1]};
        acc[0][cb] = MFMA16(vf.h, bf0.h, acc[0][cb]);
        acc[1][cb] = MFMA16(vf.h, bf1.h, acc[1][cb]);
      }
    }
  }
#pragma unroll
  for (int nh = 0; nh < 2; ++nh) {
    lsum[nh] += __shfl_xor(lsum[nh], 16);
    lsum[nh] += __shfl_xor(lsum[nh], 32);
  }
  // epilogue: acc[nh][cb][r] = O[c = cb*16+qd*4+r][n = n00+w*32+nh*16+l15]
  unsigned short* pab = pa + (size_t)(b * nsplit + split) * 4096 * 128;
#pragma unroll
  for (int nh = 0; nh < 2; ++nh) {
    const int n = n00 + w * 32 + nh * 16 + l15;
#pragma unroll
    for (int cb = 0; cb < 8; ++cb) {
      const int c0 = cb * 16 + qd * 4;
      u32x2 h = {pkbf(acc[nh][cb][0], acc[nh][cb][1]), pkbf(acc[nh][cb][2], acc[nh][cb][3])};
      *(u32x2*)&pab[(size_t)n * 128 + c0] = h;
    }
    if (L < 16) lp[(size_t)(b * nsplit + split) * 4096 + n00 + w * 32 + nh * 16 + l15] = lsum[nh];
  }
}

// ---------------------------------------------------------------- kernel 3
// out[b,c,n] = gamma * (sum_s pa[s][n][c]) / (sum_s lp[s][n]) + xf[b,c,n]
__global__ __launch_bounds__(256) void combine_kernel(
    const unsigned short* __restrict__ pa, const float* __restrict__ lp,
    const float* __restrict__ xf, const float* __restrict__ gamma_p,
    float* __restrict__ out, int nsplit) {
  __shared__ float tile[64 * 129];
  __shared__ float linv[64];
  const int tid = threadIdx.x;
  const int n0 = blockIdx.x * 64;
  const int b = blockIdx.y;

  const unsigned short* a0 = pa + ((size_t)(b * nsplit) * 4096 + n0) * 128;
#pragma unroll
  for (int i = 0; i < 8; ++i) {
    const int v = tid + i * 256;           // 2048 quads = 64n x 128c
    const int n = v >> 5, cw = (v & 31) * 4;
    f32x4 s = (f32x4){0.f, 0.f, 0.f, 0.f};
    for (int sp = 0; sp < nsplit; ++sp) {
      u16x4 h = *(const u16x4*)(a0 + (size_t)sp * 4096 * 128 + (size_t)n * 128 + cw);
#pragma unroll
      for (int j = 0; j < 4; ++j) s[j] += __uint_as_float((unsigned int)h[j] << 16);
    }
    float* t = &tile[n * 129 + cw];
    t[0] = s[0]; t[1] = s[1]; t[2] = s[2]; t[3] = s[3];
  }
  if (tid < 64) {
    float l = 0.f;
    for (int sp = 0; sp < nsplit; ++sp)
      l += lp[(size_t)(b * nsplit + sp) * 4096 + n0 + tid];
    linv[tid] = gamma_p[0] / l;
  }
  __syncthreads();
  const size_t ob = (size_t)b * 128 * 4096;
#pragma unroll
  for (int i = 0; i < 8; ++i) {
    const int v = tid + i * 256;           // 2048 quads = 128c x 16 n-quads
    const int c = v >> 4, nq = (v & 15) * 4;
    f32x4 xv = *(const f32x4*)(xf + ob + (size_t)c * 4096 + n0 + nq);
    f32x4 o;
#pragma unroll
    for (int j = 0; j < 4; ++j)
      o[j] = tile[(nq + j) * 129 + c] * linv[nq + j] + xv[j];
    *(f32x4*)(out + ob + (size_t)c * 4096 + n0 + nq) = o;
  }
}

// ---------------------------------------------------------------- launcher
extern "C" void kernel_launch(void* const* d_in, const int* in_sizes, int n_in,
                              void* d_out, int out_size, void* d_ws, size_t ws_size,
                              hipStream_t stream) {
  const float* x    = (const float*)d_in[0];
  const float* W_in = (const float*)d_in[1];
  const float* b_in = (const float*)d_in[2];
  const float* W_q  = (const float*)d_in[3];
  const float* b_q  = (const float*)d_in[4];
  const float* W_k  = (const float*)d_in[5];
  const float* b_k  = (const float*)d_in[6];
  const float* W_v  = (const float*)d_in[7];
  const float* b_v  = (const float*)d_in[8];
  const float* gam  = (const float*)d_in[9];
  float* out = (float*)d_out;

  char* ws = (char*)d_ws;
  unsigned short* Wb = (unsigned short*)ws;                 // Win|Wq|Wk|Wv bf16
  float* xf          = (float*)(ws + 262144);               // (8,128,4096) f32
  unsigned short* qt = (unsigned short*)(ws + 262144 + 16777216);  // (8,4096,128)
  unsigned short* kt = qt + (size_t)8 * 4096 * 128;
  unsigned short* vv = kt + (size_t)8 * 4096 * 128;
  const size_t base_end = 262144 + 16777216 + 3ull * 8388608;      // 42,205,184
  float* lp          = (float*)(ws + base_end);             // (8,ns<=4,4096) f32
  unsigned short* pa = (unsigned short*)(ws + base_end + 524288);  // (8,ns,4096,128) bf16

  const size_t fixed = base_end + 524288;
  const int nsplit = (ws_size >= fixed + 4ull * 8388608) ? 4
                   : (ws_size >= fixed + 2ull * 8388608) ? 2 : 1;

  cvt_w_kernel<<<448, 256, 0, stream>>>(W_in, W_q, W_k, W_v, Wb);
  proj_kernel<<<dim3(64, 8), 256, 0, stream>>>(x, Wb, b_in, b_q, b_k, b_v,
                                               xf, qt, kt, vv);
  attn_kernel<<<256 * nsplit, 256, 0, stream>>>(qt, kt, vv, pa, lp, nsplit);
  combine_kernel<<<dim3(64, 8), 256, 0, stream>>>(pa, lp, xf, gam, out, nsplit);
}

// Round 6
// 247.456 us; speedup vs baseline: 1.4242x; 1.4242x over previous
//
#include <hip/hip_runtime.h>

// Fused SAGAN attention block, MI355X/gfx950.
// B=8, C=128, N=4096 (64x64), IN=512. bf16 MFMA 16x16x32, fp32 accum.
// Fragment layouts (verified rounds 1-5 pass):
//   A-frag: A[m = lane&15][k = (lane>>4)*8 + j]   (short8, 16B/lane)
//   B-frag: B[k = (lane>>4)*8 + j][n = lane&15]
//   C/D   : D[row = (lane>>4)*4 + reg][col = lane&15]
// R6: (a) attn launch_bounds(256,3) -> 168 regs/wave, no spills (R5's (256,4)
// capped at 128 and spilled ~700MB/dispatch to scratch); (b) vv stored with
// per-32-chunk m-permutation sigma(m)=qd*8+hi*4+(m&3) so the permuted-k-map
// PV V-frag is ONE ds_read_b128 at L*8 (R5 used 2x b64, 2x instrs+conflicts);
// (c) all weights stored in frag-block layout (16o x 32i blocks, lane-L
// contiguous) so every weight frag load is a coalesced 1KB/wave dwordx4
// (was 16-way split per instr, repeated every K-chunk in proj).

typedef __attribute__((ext_vector_type(4))) float f32x4;
typedef __attribute__((ext_vector_type(8))) short bf16x8;
typedef __attribute__((ext_vector_type(2))) unsigned int u32x2;
typedef __attribute__((ext_vector_type(4))) unsigned int u32x4;
typedef __attribute__((ext_vector_type(4))) unsigned short u16x4;

#define MFMA16(a, b, c) __builtin_amdgcn_mfma_f32_16x16x32_bf16((a), (b), (c), 0, 0, 0)
#define LOG2E 1.44269504088896340736f
#define SOFTMAX_SHIFT 40.0f

#if __has_builtin(__builtin_amdgcn_exp2f)
#define EXP2F(x) __builtin_amdgcn_exp2f(x)
#else
#define EXP2F(x) exp2f(x)
#endif

__device__ __forceinline__ unsigned short f2bf(float f) {
  union { float f; unsigned int u; } v; v.f = f;
  unsigned int r = v.u + 0x7FFFu + ((v.u >> 16) & 1u);  // RNE
  return (unsigned short)(r >> 16);
}

// pack two f32 -> packed bf16x2 (round-half-up): 2 adds + 1 v_perm_b32.
__device__ __forceinline__ unsigned int pkbf(float a, float b) {
  unsigned int ua = __float_as_uint(a) + 0x8000u;
  unsigned int ub = __float_as_uint(b) + 0x8000u;
  return __builtin_amdgcn_perm(ub, ua, 0x07060302u);  // lo=bf(a), hi=bf(b)
}

__device__ __forceinline__ void gload_lds16(const void* g, void* l) {
  __builtin_amdgcn_global_load_lds(
      (const __attribute__((address_space(1))) unsigned int*)(unsigned long long)g,
      (__attribute__((address_space(3))) unsigned int*)(unsigned int)(unsigned long long)l,
      16, 0, 0);
}

union frag_cast { u32x4 u; bf16x8 h; };

// ---------------------------------------------------------------- kernel 0
// fp32 weights -> bf16 in FRAG-BLOCK layout: block (o>>4, i>>5) of 512 shorts;
// within: lane L = ((i>>3)&3)*16 + (o&15) at L*8 + (i&7). A frag load for a
// (16-row, 32-col) piece is then 64 lanes x 16B contiguous.
__global__ void cvt_w_kernel(const float* __restrict__ Win, const float* __restrict__ Wq,
                             const float* __restrict__ Wk, const float* __restrict__ Wv,
                             unsigned short* __restrict__ o) {
  int t = blockIdx.x * 256 + threadIdx.x;
  float v; int oo, ii, nchunk, base;
  if (t < 65536)       { v = Win[t]; oo = t >> 9; ii = t & 511; nchunk = 16; base = 0; }
  else if (t < 81920)  { int u = t - 65536; v = Wq[u]; oo = u >> 7; ii = u & 127; nchunk = 4; base = 65536; }
  else if (t < 98304)  { int u = t - 81920; v = Wk[u]; oo = u >> 7; ii = u & 127; nchunk = 4; base = 81920; }
  else if (t < 114688) { int u = t - 98304; v = Wv[u]; oo = u >> 7; ii = u & 127; nchunk = 4; base = 98304; }
  else return;
  int idx = ((oo >> 4) * nchunk + (ii >> 5)) * 512 + ((ii >> 3) & 3) * 128 + (oo & 15) * 8 + (ii & 7);
  o[base + idx] = f2bf(v);
}

// ---------------------------------------------------------------- kernel 1
// Fused projections, 64-n tile per 256-thread block (grid 64x8).
// xf = W_in x + b_in (fp32 (C,N)); xh tile in LDS; q,k (N,C); v (C,N)
// with sigma-permuted m within each 32-chunk (matches attn's PV k-map).
__global__ __launch_bounds__(256) void proj_kernel(
    const float* __restrict__ x, const unsigned short* __restrict__ Wb,
    const float* __restrict__ b_in, const float* __restrict__ bq,
    const float* __restrict__ bk, const float* __restrict__ bv,
    float* __restrict__ xf, unsigned short* __restrict__ qt,
    unsigned short* __restrict__ kt, unsigned short* __restrict__ vv) {
  __shared__ alignas(16) unsigned short xt[16 * 512];   // x chunk 128i x 64n, swizzled
  __shared__ alignas(16) unsigned short xt2[16 * 512];  // xh tile 128c x 64n
  const int tid = threadIdx.x;
  const int w = tid >> 6, L = tid & 63, l15 = L & 15, qd = L >> 4;
  const int n0 = blockIdx.x * 64;
  const int b = blockIdx.y;
  const float* xb = x + (size_t)b * 512 * 4096;

  const int io = tid >> 4, nq = tid & 15;          // i-oct 0..15, n-quad 0..15
  const int il0 = io * 8, kkA = io >> 2, qr = io & 3;
  const int nbA = nq >> 2;
  const int Lsw8 = (L ^ ((L >> 2) & 7)) * 8;       // swizzled read slot

  f32x4 acc[2][4];
#pragma unroll
  for (int ma = 0; ma < 2; ++ma)
#pragma unroll
    for (int nb = 0; nb < 4; ++nb) acc[ma][nb] = (f32x4){0.f, 0.f, 0.f, 0.f};

  f32x4 xv[8];
#pragma unroll
  for (int r = 0; r < 8; ++r)
    xv[r] = *(const f32x4*)(xb + (size_t)(il0 + r) * 4096 + n0 + nq * 4);

  for (int c4 = 0; c4 < 4; ++c4) {
    __syncthreads();
#pragma unroll
    for (int j = 0; j < 4; ++j) {
      const int n15 = (nq & 3) * 4 + j;
      const int s = qr * 16 + n15;
      const int sp = s ^ ((s >> 2) & 7);           // bank swizzle
      u32x4 d = {pkbf(xv[0][j], xv[1][j]), pkbf(xv[2][j], xv[3][j]),
                 pkbf(xv[4][j], xv[5][j]), pkbf(xv[6][j], xv[7][j])};
      *(u32x4*)&xt[(nbA * 4 + kkA) * 512 + sp * 8] = d;
    }
    __syncthreads();
    if (c4 < 3) {                                  // prefetch next chunk
      const int i0n = (c4 + 1) * 128;
#pragma unroll
      for (int r = 0; r < 8; ++r)
        xv[r] = *(const f32x4*)(xb + (size_t)(i0n + il0 + r) * 4096 + n0 + nq * 4);
    }
#pragma unroll
    for (int kk = 0; kk < 4; ++kk) {
      bf16x8 a[2];
#pragma unroll
      for (int ma = 0; ma < 2; ++ma)   // frag-block layout: coalesced 1KB/wave
        a[ma] = *(const bf16x8*)(Wb + (size_t)((w * 2 + ma) * 16 + c4 * 4 + kk) * 512 + L * 8);
#pragma unroll
      for (int nb = 0; nb < 4; ++nb) {
        bf16x8 bfv = *(const bf16x8*)&xt[(nb * 4 + kk) * 512 + Lsw8];
#pragma unroll
        for (int ma = 0; ma < 2; ++ma) acc[ma][nb] = MFMA16(a[ma], bfv, acc[ma][nb]);
      }
    }
  }
  // epilogue A: xf (fp32 global) + xh tile into xt2 (B-frag order)
  {
    float* xfb = xf + (size_t)b * 128 * 4096;
#pragma unroll
    for (int ma = 0; ma < 2; ++ma) {
      const int c0 = w * 32 + ma * 16 + qd * 4;
      const float bi0 = b_in[c0], bi1 = b_in[c0 + 1], bi2 = b_in[c0 + 2], bi3 = b_in[c0 + 3];
      const int qdrow = ma * 2 + (qd >> 1);
      const int joff = (qd & 1) * 4;
#pragma unroll
      for (int nb = 0; nb < 4; ++nb) {
        const int n = n0 + nb * 16 + l15;
        const float v0 = acc[ma][nb][0] + bi0, v1 = acc[ma][nb][1] + bi1;
        const float v2 = acc[ma][nb][2] + bi2, v3 = acc[ma][nb][3] + bi3;
        xfb[(size_t)(c0 + 0) * 4096 + n] = v0;
        xfb[(size_t)(c0 + 1) * 4096 + n] = v1;
        xfb[(size_t)(c0 + 2) * 4096 + n] = v2;
        xfb[(size_t)(c0 + 3) * 4096 + n] = v3;
        u32x2 h = {pkbf(v0, v1), pkbf(v2, v3)};
        *(u32x2*)&xt2[(nb * 4 + w) * 512 + qdrow * 128 + l15 * 8 + joff] = h;
      }
    }
  }
  __syncthreads();

  // ---- phase B: q, k (M = c strip w*32..+32, N = n 64)
  for (int which = 0; which < 2; ++which) {
    const unsigned short* W = Wb + 65536 + which * 16384;
    const float* bias = which ? bk : bq;
    unsigned short* dst = (which ? kt : qt) + (size_t)b * 4096 * 128;
    f32x4 a2[2][4];
#pragma unroll
    for (int ma = 0; ma < 2; ++ma)
#pragma unroll
      for (int nb = 0; nb < 4; ++nb) a2[ma][nb] = (f32x4){0.f, 0.f, 0.f, 0.f};
#pragma unroll
    for (int kk = 0; kk < 4; ++kk) {
      bf16x8 a[2];
#pragma unroll
      for (int ma = 0; ma < 2; ++ma)   // frag-block layout: coalesced
        a[ma] = *(const bf16x8*)(W + (size_t)((w * 2 + ma) * 4 + kk) * 512 + L * 8);
#pragma unroll
      for (int nb = 0; nb < 4; ++nb) {
        bf16x8 bfv = *(const bf16x8*)&xt2[(nb * 4 + kk) * 512 + L * 8];
#pragma unroll
        for (int ma = 0; ma < 2; ++ma) a2[ma][nb] = MFMA16(a[ma], bfv, a2[ma][nb]);
      }
    }
#pragma unroll
    for (int ma = 0; ma < 2; ++ma) {
      const int c0 = w * 32 + ma * 16 + qd * 4;
      const float b0 = bias[c0], b1 = bias[c0 + 1], b2 = bias[c0 + 2], b3 = bias[c0 + 3];
#pragma unroll
      for (int nb = 0; nb < 4; ++nb) {
        const int n = n0 + nb * 16 + l15;
        u32x2 h = {pkbf(a2[ma][nb][0] + b0, a2[ma][nb][1] + b1),
                   pkbf(a2[ma][nb][2] + b2, a2[ma][nb][3] + b3)};
        *(u32x2*)&dst[(size_t)n * 128 + c0] = h;
      }
    }
  }
  // ---- phase B: v (M = n strip w*16, N = c 128) -> channel-major, sigma-permuted
  {
    const unsigned short* Wv = Wb + 98304;
    f32x4 a2[8];
#pragma unroll
    for (int cb = 0; cb < 8; ++cb) a2[cb] = (f32x4){0.f, 0.f, 0.f, 0.f};
#pragma unroll
    for (int kk = 0; kk < 4; ++kk) {
      bf16x8 a = *(const bf16x8*)&xt2[(w * 4 + kk) * 512 + L * 8];  // A-frag: n-strip w
#pragma unroll
      for (int cb = 0; cb < 8; ++cb) {
        bf16x8 bfv = *(const bf16x8*)(Wv + (size_t)(cb * 4 + kk) * 512 + L * 8);
        a2[cb] = MFMA16(a, bfv, a2[cb]);
      }
    }
    unsigned short* db = vv + (size_t)b * 128 * 4096;
    // sigma within each 32-chunk: stored = qd_m*8 + hi*4 + (m&3)
    const int sn = n0 + ((w >> 1) << 5) + qd * 8 + ((w & 1) << 2);
#pragma unroll
    for (int cb = 0; cb < 8; ++cb) {
      const int c = cb * 16 + l15;
      const float bvv = bv[c];
      u32x2 h = {pkbf(a2[cb][0] + bvv, a2[cb][1] + bvv), pkbf(a2[cb][2] + bvv, a2[cb][3] + bvv)};
      *(u32x2*)&db[(size_t)c * 4096 + sn] = h;
    }
  }
}

// ---------------------------------------------------------------- kernel 2
// Flash attention, no-max softmax. Block = (batch, 128-q tile, m-split).
// K,V staged in LDS (32KB). PV B-operand = own packed S^T C/D regs (permuted
// k-map); V A-frag = single b128 (vv pre-permuted by sigma). pa bf16 (N,C).
__global__ __launch_bounds__(256, 3) void attn_kernel(
    const unsigned short* __restrict__ qt, const unsigned short* __restrict__ kt,
    const unsigned short* __restrict__ vv, unsigned short* __restrict__ pa,
    float* __restrict__ lp, int nsplit) {
  __shared__ alignas(16) unsigned short kbuf[16 * 512];   // 16 KB (mb, kk)
  __shared__ alignas(16) unsigned short vbuf[16 * 512];   // 16 KB (cb, ks)

  const int tid = threadIdx.x;
  const int w = tid >> 6, L = tid & 63, l15 = L & 15, qd = L >> 4;
  const int bidx = blockIdx.x;
  const int b = bidx & 7;                  // XCD-pinned batch: K/V L2-resident
  const int r2 = bidx >> 3;
  const int qtile = r2 & 31, split = r2 >> 5;
  const int n00 = qtile * 128;
  const int mlen = 4096 / nsplit;
  const int mbeg = split * mlen;

  const unsigned short* qtb = qt + (size_t)b * 4096 * 128;
  const unsigned short* ktb = kt + (size_t)b * 4096 * 128;
  const unsigned short* vvb = vv + (size_t)b * 128 * 4096;

  bf16x8 qf[2][4];
#pragma unroll
  for (int nh = 0; nh < 2; ++nh) {
    const unsigned short* qrow = qtb + (size_t)(n00 + w * 32 + nh * 16 + l15) * 128 + qd * 8;
#pragma unroll
    for (int kk = 0; kk < 4; ++kk) qf[nh][kk] = *(const bf16x8*)(qrow + kk * 32);
  }

  f32x4 acc[2][8];
#pragma unroll
  for (int nh = 0; nh < 2; ++nh)
#pragma unroll
    for (int cb = 0; cb < 8; ++cb) acc[nh][cb] = (f32x4){0.f, 0.f, 0.f, 0.f};
  float lsum[2] = {0.f, 0.f};
  const float sb = SOFTMAX_SHIFT * LOG2E;

  for (int m0 = mbeg; m0 < mbeg + mlen; m0 += 64) {
    __syncthreads();                       // prev iter's kbuf/vbuf reads done
#pragma unroll
    for (int j = 0; j < 4; ++j) {
      const int blk = w * 4 + j;
      const int mb = blk >> 2, kk = blk & 3;
      gload_lds16(ktb + (size_t)(m0 + mb * 16 + l15) * 128 + kk * 32 + qd * 8,
                  &kbuf[blk * 512]);
      const int cb2 = blk >> 1, ks = blk & 1;
      gload_lds16(vvb + (size_t)(cb2 * 16 + l15) * 4096 + m0 + ks * 32 + qd * 8,
                  &vbuf[blk * 512]);
    }
    __syncthreads();                       // staging complete

    // S^T = K · Q^T : D rows = m-local, cols = n-local (per nh half)
    f32x4 s[2][4];
#pragma unroll
    for (int mb = 0; mb < 4; ++mb) {
      s[0][mb] = (f32x4){0.f, 0.f, 0.f, 0.f};
      s[1][mb] = (f32x4){0.f, 0.f, 0.f, 0.f};
#pragma unroll
      for (int kk = 0; kk < 4; ++kk) {
        bf16x8 kf = *(const bf16x8*)&kbuf[(mb * 4 + kk) * 512 + L * 8];
        s[0][mb] = MFMA16(kf, qf[0][kk], s[0][mb]);
        s[1][mb] = MFMA16(kf, qf[1][kk], s[1][mb]);
      }
    }
    // p = exp2(s*log2e - shift); lane-local row sums; pack into OWN regs.
    unsigned int pk01[2][4], pk23[2][4];
#pragma unroll
    for (int nh = 0; nh < 2; ++nh) {
#pragma unroll
      for (int mb = 0; mb < 4; ++mb) {
        float p0 = EXP2F(__builtin_fmaf(s[nh][mb][0], LOG2E, -sb));
        float p1 = EXP2F(__builtin_fmaf(s[nh][mb][1], LOG2E, -sb));
        float p2 = EXP2F(__builtin_fmaf(s[nh][mb][2], LOG2E, -sb));
        float p3 = EXP2F(__builtin_fmaf(s[nh][mb][3], LOG2E, -sb));
        lsum[nh] += (p0 + p1) + (p2 + p3);
        pk01[nh][mb] = pkbf(p0, p1);
        pk23[nh][mb] = pkbf(p2, p3);
      }
    }
    // O[c][n] += V · P^T, k-map pi(qd*8+j) = (j>=4)*16 + qd*4 + (j&3).
    // V A-frag = single b128 (sigma-permuted vv matches pi exactly).
#pragma unroll
    for (int ks = 0; ks < 2; ++ks) {
      frag_cast bf0, bf1;
      bf0.u = (u32x4){pk01[0][ks * 2], pk23[0][ks * 2], pk01[0][ks * 2 + 1], pk23[0][ks * 2 + 1]};
      bf1.u = (u32x4){pk01[1][ks * 2], pk23[1][ks * 2], pk01[1][ks * 2 + 1], pk23[1][ks * 2 + 1]};
#pragma unroll
      for (int cb = 0; cb < 8; ++cb) {
        bf16x8 vf = *(const bf16x8*)&vbuf[(cb * 2 + ks) * 512 + L * 8];
        acc[0][cb] = MFMA16(vf, bf0.h, acc[0][cb]);
        acc[1][cb] = MFMA16(vf, bf1.h, acc[1][cb]);
      }
    }
  }
#pragma unroll
  for (int nh = 0; nh < 2; ++nh) {
    lsum[nh] += __shfl_xor(lsum[nh], 16);
    lsum[nh] += __shfl_xor(lsum[nh], 32);
  }
  // epilogue: acc[nh][cb][r] = O[c = cb*16+qd*4+r][n = n00+w*32+nh*16+l15]
  unsigned short* pab = pa + (size_t)(b * nsplit + split) * 4096 * 128;
#pragma unroll
  for (int nh = 0; nh < 2; ++nh) {
    const int n = n00 + w * 32 + nh * 16 + l15;
#pragma unroll
    for (int cb = 0; cb < 8; ++cb) {
      const int c0 = cb * 16 + qd * 4;
      u32x2 h = {pkbf(acc[nh][cb][0], acc[nh][cb][1]), pkbf(acc[nh][cb][2], acc[nh][cb][3])};
      *(u32x2*)&pab[(size_t)n * 128 + c0] = h;
    }
    if (L < 16) lp[(size_t)(b * nsplit + split) * 4096 + n00 + w * 32 + nh * 16 + l15] = lsum[nh];
  }
}

// ---------------------------------------------------------------- kernel 3
// out[b,c,n] = gamma * (sum_s pa[s][n][c]) / (sum_s lp[s][n]) + xf[b,c,n]
__global__ __launch_bounds__(256) void combine_kernel(
    const unsigned short* __restrict__ pa, const float* __restrict__ lp,
    const float* __restrict__ xf, const float* __restrict__ gamma_p,
    float* __restrict__ out, int nsplit) {
  __shared__ float tile[64 * 129];
  __shared__ float linv[64];
  const int tid = threadIdx.x;
  const int n0 = blockIdx.x * 64;
  const int b = blockIdx.y;

  const unsigned short* a0 = pa + ((size_t)(b * nsplit) * 4096 + n0) * 128;
#pragma unroll
  for (int i = 0; i < 8; ++i) {
    const int v = tid + i * 256;           // 2048 quads = 64n x 128c
    const int n = v >> 5, cw = (v & 31) * 4;
    f32x4 s = (f32x4){0.f, 0.f, 0.f, 0.f};
    for (int sp = 0; sp < nsplit; ++sp) {
      u16x4 h = *(const u16x4*)(a0 + (size_t)sp * 4096 * 128 + (size_t)n * 128 + cw);
#pragma unroll
      for (int j = 0; j < 4; ++j) s[j] += __uint_as_float((unsigned int)h[j] << 16);
    }
    float* t = &tile[n * 129 + cw];
    t[0] = s[0]; t[1] = s[1]; t[2] = s[2]; t[3] = s[3];
  }
  if (tid < 64) {
    float l = 0.f;
    for (int sp = 0; sp < nsplit; ++sp)
      l += lp[(size_t)(b * nsplit + sp) * 4096 + n0 + tid];
    linv[tid] = gamma_p[0] / l;
  }
  __syncthreads();
  const size_t ob = (size_t)b * 128 * 4096;
#pragma unroll
  for (int i = 0; i < 8; ++i) {
    const int v = tid + i * 256;           // 2048 quads = 128c x 16 n-quads
    const int c = v >> 4, nq = (v & 15) * 4;
    f32x4 xv = *(const f32x4*)(xf + ob + (size_t)c * 4096 + n0 + nq);
    f32x4 o;
#pragma unroll
    for (int j = 0; j < 4; ++j)
      o[j] = tile[(nq + j) * 129 + c] * linv[nq + j] + xv[j];
    *(f32x4*)(out + ob + (size_t)c * 4096 + n0 + nq) = o;
  }
}

// ---------------------------------------------------------------- launcher
extern "C" void kernel_launch(void* const* d_in, const int* in_sizes, int n_in,
                              void* d_out, int out_size, void* d_ws, size_t ws_size,
                              hipStream_t stream) {
  const float* x    = (const float*)d_in[0];
  const float* W_in = (const float*)d_in[1];
  const float* b_in = (const float*)d_in[2];
  const float* W_q  = (const float*)d_in[3];
  const float* b_q  = (const float*)d_in[4];
  const float* W_k  = (const float*)d_in[5];
  const float* b_k  = (const float*)d_in[6];
  const float* W_v  = (const float*)d_in[7];
  const float* b_v  = (const float*)d_in[8];
  const float* gam  = (const float*)d_in[9];
  float* out = (float*)d_out;

  char* ws = (char*)d_ws;
  unsigned short* Wb = (unsigned short*)ws;                 // frag-layout weights
  float* xf          = (float*)(ws + 262144);               // (8,128,4096) f32
  unsigned short* qt = (unsigned short*)(ws + 262144 + 16777216);  // (8,4096,128)
  unsigned short* kt = qt + (size_t)8 * 4096 * 128;
  unsigned short* vv = kt + (size_t)8 * 4096 * 128;         // sigma-permuted (C,N)
  const size_t base_end = 262144 + 16777216 + 3ull * 8388608;      // 42,205,184
  float* lp          = (float*)(ws + base_end);             // (8,ns<=4,4096) f32
  unsigned short* pa = (unsigned short*)(ws + base_end + 524288);  // (8,ns,4096,128) bf16

  const size_t fixed = base_end + 524288;
  const int nsplit = (ws_size >= fixed + 4ull * 8388608) ? 4
                   : (ws_size >= fixed + 2ull * 8388608) ? 2 : 1;

  cvt_w_kernel<<<448, 256, 0, stream>>>(W_in, W_q, W_k, W_v, Wb);
  proj_kernel<<<dim3(64, 8), 256, 0, stream>>>(x, Wb, b_in, b_q, b_k, b_v,
                                               xf, qt, kt, vv);
  attn_kernel<<<256 * nsplit, 256, 0, stream>>>(qt, kt, vv, pa, lp, nsplit);
  combine_kernel<<<dim3(64, 8), 256, 0, stream>>>(pa, lp, xf, gam, out, nsplit);
}